// Round 9
// baseline (223.378 us; speedup 1.0000x reference)
//
#include <hip/hip_runtime.h>

// ---------------------------------------------------------------------------
// Multihead self-attention with RoPE, MI355X (gfx950).  Round 18.
// B=2, S=2048, H=16, DH=64, DM=1024.
// R18: restore TLP to the triple-merged QKV GEMM. R17 evidence: 1 block/CU
// (Occ 9%) exposed all load latency (3160 cyc/iter vs ~500 issue); density
// without occupancy is masked. Keep triple-merge (shared X staging, shared
// RoPE, 48 MFMA/wave/iter) but 2-ring (64 KB LDS) -> 2 blocks/CU,
// launch_bounds(256,2); stage issued at iteration top (full-body shadow),
// one vmcnt(0)+barrier at bottom; co-resident block hides the drain (m114
// mechanism). out_gemm reverted to the proven R15/R16 config (64x128,
// grid (64,8), 36 KB) undoing R17's uncontrolled regression.
// flash/cast byte-identical.
// ---------------------------------------------------------------------------

typedef __attribute__((ext_vector_type(8))) short bf16x8;
typedef __attribute__((ext_vector_type(4))) float f32x4;

__device__ __forceinline__ short f2bf(float f) {
  unsigned u = __float_as_uint(f);
  unsigned r = (u + 0x7fffu + ((u >> 16) & 1u)) >> 16;   // RNE
  return (short)(r & 0xFFFFu);
}

// pack two f32 -> one u32 of two bf16 (RNE, order a=low b=high)
__device__ __forceinline__ unsigned pk2rne(float a, float b) {
  return ((unsigned)(unsigned short)f2bf(b) << 16) | (unsigned short)f2bf(a);
}

// pack two f32 -> adjacent bf16 (round-half-up via +0x8000), one v_perm_b32
__device__ __forceinline__ unsigned pk2(float a, float b) {
  return __builtin_amdgcn_perm(__float_as_uint(b) + 0x8000u,
                               __float_as_uint(a) + 0x8000u, 0x07060302u);
}

// native 2^x, one v_exp_f32 (bypasses OCML guard sequence)
__device__ __forceinline__ float exp2x(float x) {
  float r;
  asm("v_exp_f32 %0, %1" : "=v"(r) : "v"(x));
  return r;
}

// async global->LDS, 16B per lane. LDS dest must be wave-uniform base + lane*16.
__device__ __forceinline__ void async16(const void* g, void* l) {
  __builtin_amdgcn_global_load_lds(
      (const __attribute__((address_space(1))) void*)g,
      (__attribute__((address_space(3))) void*)l, 16, 0, 0);
}

__device__ __forceinline__ void cstore(short* C, size_t i, float v) { C[i] = f2bf(v); }
__device__ __forceinline__ void cstore(float* C, size_t i, float v) { C[i] = v; }

// ---------------------------------------------------------------------------
// merged f32 -> bf16 cast: X (1M float4) then Wq|Wk|Wv|Wo (dsts contiguous).
// ---------------------------------------------------------------------------
__global__ void cast_all(const float4* __restrict__ X,
                         const float4* __restrict__ w0, const float4* __restrict__ w1,
                         const float4* __restrict__ w2, const float4* __restrict__ w3,
                         short* __restrict__ Xb, short* __restrict__ Wb) {
  int t = blockIdx.x * 256 + threadIdx.x;
  const float4* s;
  short4* d;
  if (t < (1 << 20)) {
    s = X + t; d = (short4*)Xb + t;
  } else {
    int u = t - (1 << 20);
    int which = u >> 18;
    s = ((which == 0) ? w0 : (which == 1) ? w1 : (which == 2) ? w2 : w3) + (u & 0x3FFFF);
    d = (short4*)Wb + u;
  }
  float4 v = *s;
  *d = make_short4(f2bf(v.x), f2bf(v.y), f2bf(v.z), f2bf(v.w));
}

// ---------------------------------------------------------------------------
// bf16 GEMM core (single-B): C[M,N] = A[M,K] * B[N,K]^T, K=1024.
// Used by out_gemm (EPI_ROW). 3-ring counted vmcnt (R10 pipeline).
// ---------------------------------------------------------------------------
enum EpiMode { EPI_ROW, EPI_KFRAG, EPI_VFRAG };

template <typename OUT, int MR, int NR, bool ROPE, EpiMode EM, bool MAPB>
__device__ __forceinline__ void gemm_core(short* __restrict__ As, short* __restrict__ Bs,
                                          const short* __restrict__ A, const short* __restrict__ B,
                                          OUT* __restrict__ C, int bm, int bn, int ldc,
                                          const int* __restrict__ pos) {
  constexpr int BM = 32 * MR, BN = 32 * NR;
  constexpr int NLD = (BM * 4 + BN * 4) / 256;   // global_load_lds per wave per stage
  const int tid  = threadIdx.x;
  const int lane = tid & 63, wave = tid >> 6;
  const int col  = lane & 15, quad = lane >> 4;
  const int wm = (wave & 1) * (16 * MR), wn = (wave >> 1) * (16 * NR);

  f32x4 acc[MR][NR];
#pragma unroll
  for (int i = 0; i < MR; i++)
#pragma unroll
    for (int j = 0; j < NR; j++) acc[i][j] = (f32x4){0.f, 0.f, 0.f, 0.f};

  auto stage = [&](int k0, int bu) {
#pragma unroll
    for (int c = tid; c < BM * 4; c += 256) {
      int r = c >> 2, cc = (c & 3) << 3;
      async16(A + (size_t)(bm + r) * 1024 + k0 + cc, As + bu * BM * 32 + c * 8);
    }
#pragma unroll
    for (int c = tid; c < BN * 4; c += 256) {
      int r = c >> 2, cc = (c & 3) << 3;
      int rg = bn + r;
      if (MAPB) {
        int k6 = rg & 63;
        rg = (rg & ~63) | ((k6 < 32) ? (k6 << 1) : (((k6 - 32) << 1) | 1));
      }
      async16(B + (size_t)rg * 1024 + k0 + cc, Bs + bu * BN * 32 + c * 8);
    }
  };

  stage(0, 0);
  stage(32, 1);
  if constexpr (NLD == 4) asm volatile("s_waitcnt vmcnt(4)" ::: "memory");
  else                    asm volatile("s_waitcnt vmcnt(3)" ::: "memory");
  __builtin_amdgcn_s_barrier();

  int cur = 0, nxt = 2;
  for (int it = 0; it < 32; ++it) {
    if (it < 30) stage((it + 2) * 32, nxt);
    const short* as = As + cur * (BM * 32);
    const short* bs = Bs + cur * (BN * 32);

    bf16x8 af[MR], bfr[NR];
#pragma unroll
    for (int i = 0; i < MR; i++)
      af[i] = *(const bf16x8*)(as + (wm + i * 16 + col) * 32 + quad * 8);
#pragma unroll
    for (int i = 0; i < NR; i++)
      bfr[i] = *(const bf16x8*)(bs + (wn + i * 16 + col) * 32 + quad * 8);
#pragma unroll
    for (int mi = 0; mi < MR; mi++)
#pragma unroll
      for (int ni = 0; ni < NR; ni++)
        acc[mi][ni] = __builtin_amdgcn_mfma_f32_16x16x32_bf16(af[mi], bfr[ni], acc[mi][ni], 0, 0, 0);

    if (it < 30) {
      if constexpr (NLD == 4) asm volatile("s_waitcnt vmcnt(4)" ::: "memory");
      else                    asm volatile("s_waitcnt vmcnt(3)" ::: "memory");
    } else {
      asm volatile("s_waitcnt vmcnt(0)" ::: "memory");
    }
    __builtin_amdgcn_s_barrier();
    cur = (cur == 2) ? 0 : cur + 1;
    nxt = (nxt == 2) ? 0 : nxt + 1;
  }

  if (EM == EPI_ROW) {
#pragma unroll
    for (int mi = 0; mi < MR; mi++) {
#pragma unroll
      for (int r = 0; r < 4; r++) {
        size_t row = (size_t)(bm + wm + mi * 16 + quad * 4 + r);
#pragma unroll
        for (int ni = 0; ni < NR; ni++) {
          int cg = bn + wn + ni * 16 + col;
          cstore(C, row * ldc + cg, acc[mi][ni][r]);
        }
      }
    }
  }
}

// ---------------------------------------------------------------------------
// Triple-merged GEMM: Q = rope(X Wq^T) row-major, Kf = rope(X Wk^T)
// frag-major, Vf = (X Wv^T) frag-major — all sharing the A=X tile.
// BM=BN=128, BK=32, 2-ring (64 KB LDS), 8 async16/thread/stage.
// Stage issued at iteration TOP (full-body shadow); vmcnt(0)+barrier at
// bottom. Grid (32,8), 2 blocks/CU.
// ---------------------------------------------------------------------------
__global__ __launch_bounds__(256, 2) void qkv_gemm(const short* __restrict__ Xb,
                                                   const short* __restrict__ Wq,
                                                   const short* __restrict__ Wk,
                                                   const short* __restrict__ Wv,
                                                   short* __restrict__ Qo,
                                                   short* __restrict__ Kf,
                                                   short* __restrict__ Vf,
                                                   const int* __restrict__ pos) {
  __shared__ __align__(16) short sm[32768];   // 64 KB: A|Bq|Bk|Bv x 2-ring
  short* As  = sm;
  short* Bqs = sm + 8192;
  short* Bks = sm + 16384;
  short* Bvs = sm + 24576;

  const int bm = blockIdx.x * 128, bn = blockIdx.y * 128;
  const int tid  = threadIdx.x;
  const int lane = tid & 63, wave = tid >> 6;
  const int col  = lane & 15, quad = lane >> 4;
  const int wm = (wave & 1) * 64, wn = (wave >> 1) * 64;

  f32x4 aq[4][4], ak[4][4], av[4][4];
#pragma unroll
  for (int i = 0; i < 4; i++)
#pragma unroll
    for (int j = 0; j < 4; j++) {
      aq[i][j] = (f32x4){0.f, 0.f, 0.f, 0.f};
      ak[i][j] = (f32x4){0.f, 0.f, 0.f, 0.f};
      av[i][j] = (f32x4){0.f, 0.f, 0.f, 0.f};
    }

  auto stage = [&](int k0, int bu) {
#pragma unroll
    for (int c = tid; c < 512; c += 256) {
      int r = c >> 2, cc = (c & 3) << 3;
      async16(Xb + (size_t)(bm + r) * 1024 + k0 + cc, As + bu * 4096 + c * 8);
    }
#pragma unroll
    for (int c = tid; c < 512; c += 256) {
      int r = c >> 2, cc = (c & 3) << 3;
      int rg = bn + r;
      int k6 = rg & 63;
      int rp = (rg & ~63) | ((k6 < 32) ? (k6 << 1) : (((k6 - 32) << 1) | 1));
      async16(Wq + (size_t)rp * 1024 + k0 + cc, Bqs + bu * 4096 + c * 8);
      async16(Wk + (size_t)rp * 1024 + k0 + cc, Bks + bu * 4096 + c * 8);
      async16(Wv + (size_t)rg * 1024 + k0 + cc, Bvs + bu * 4096 + c * 8);   // no perm
    }
  };

  stage(0, 0);
  asm volatile("s_waitcnt vmcnt(0)" ::: "memory");
  __builtin_amdgcn_s_barrier();

  for (int it = 0; it < 32; ++it) {
    const int cur = it & 1;
    // prefetch next K-step FIRST: loads get the whole body as shadow
    if (it < 31) stage((it + 1) * 32, cur ^ 1);

    const short* as = As + cur * 4096;
    const short* bq = Bqs + cur * 4096;
    const short* bk = Bks + cur * 4096;
    const short* bv = Bvs + cur * 4096;

    bf16x8 af[4], bfq[4], bfk[4], bfv[4];
#pragma unroll
    for (int i = 0; i < 4; i++)
      af[i] = *(const bf16x8*)(as + (wm + i * 16 + col) * 32 + quad * 8);
#pragma unroll
    for (int i = 0; i < 4; i++) {
      bfq[i] = *(const bf16x8*)(bq + (wn + i * 16 + col) * 32 + quad * 8);
      bfk[i] = *(const bf16x8*)(bk + (wn + i * 16 + col) * 32 + quad * 8);
      bfv[i] = *(const bf16x8*)(bv + (wn + i * 16 + col) * 32 + quad * 8);
    }
    __builtin_amdgcn_s_setprio(1);
#pragma unroll
    for (int mi = 0; mi < 4; mi++)
#pragma unroll
      for (int ni = 0; ni < 4; ni++) {
        aq[mi][ni] = __builtin_amdgcn_mfma_f32_16x16x32_bf16(af[mi], bfq[ni], aq[mi][ni], 0, 0, 0);
        ak[mi][ni] = __builtin_amdgcn_mfma_f32_16x16x32_bf16(af[mi], bfk[ni], ak[mi][ni], 0, 0, 0);
        av[mi][ni] = __builtin_amdgcn_mfma_f32_16x16x32_bf16(af[mi], bfv[ni], av[mi][ni], 0, 0, 0);
      }
    __builtin_amdgcn_s_setprio(0);

    if (it < 31) {
      asm volatile("s_waitcnt vmcnt(0)" ::: "memory");   // prefetch landed
      __builtin_amdgcn_s_barrier();
    }
  }

  // shared RoPE for Q and K (d-permuted layout: pair = (acc[ni], acc[ni+2]))
  float invf[2];
#pragma unroll
  for (int ni = 0; ni < 2; ni++) {
    int p = ni * 16 + col;
    invf[ni] = exp2f(-0.4152410118609203f * (float)p) * 0.15915494309189535f;
  }
#pragma unroll
  for (int mi = 0; mi < 4; mi++) {
#pragma unroll
    for (int r = 0; r < 4; r++) {
      int row = bm + wm + mi * 16 + quad * 4 + r;
      float fp = (float)pos[row & 2047];
#pragma unroll
      for (int ni = 0; ni < 2; ni++) {
        float rev = fp * invf[ni];
        rev -= floorf(rev);
        float sn = __builtin_amdgcn_sinf(rev);
        float cs = __builtin_amdgcn_cosf(rev);
        float xq = aq[mi][ni][r], yq = aq[mi][ni + 2][r];
        aq[mi][ni][r]     = fmaf(xq, cs, -yq * sn);
        aq[mi][ni + 2][r] = fmaf(yq, cs, xq * sn);
        float xk = ak[mi][ni][r], yk = ak[mi][ni + 2][r];
        ak[mi][ni][r]     = fmaf(xk, cs, -yk * sn);
        ak[mi][ni + 2][r] = fmaf(yk, cs, xk * sn);
      }
    }
  }

  // Q epilogue: row-major
#pragma unroll
  for (int mi = 0; mi < 4; mi++) {
#pragma unroll
    for (int r = 0; r < 4; r++) {
      size_t row = (size_t)(bm + wm + mi * 16 + quad * 4 + r);
#pragma unroll
      for (int ni = 0; ni < 4; ni++) {
        int cg = bn + wn + ni * 16 + col;
        Qo[row * 1024 + cg] = f2bf(aq[mi][ni][r]);
      }
    }
  }
  // K epilogue: fragment-major (rows m = tokens, cols e = embed)
#pragma unroll
  for (int mi = 0; mi < 4; mi++) {
#pragma unroll
    for (int r = 0; r < 4; r++) {
      int m = bm + wm + mi * 16 + quad * 4 + r;
      int bq2 = m >> 11, key = m & 2047;
      int kt = key >> 6, nb = (key >> 4) & 3, cl = key & 15;
#pragma unroll
      for (int ni = 0; ni < 4; ni++) {
        int e = bn + wn + ni * 16 + col;
        int h = e >> 6, d = e & 63;
        size_t seg = ((((size_t)(bq2 * 16 + h) * 32 + kt) * 4 + nb) * 2 + (d >> 5));
        Kf[seg * 512 + (((d >> 3) & 3) * 16 + cl) * 8 + (d & 7)] = f2bf(ak[mi][ni][r]);
      }
    }
  }
  // V epilogue: fragment-major from (m rows, e cols) orientation.
  {
    const int k7base = (quad & 1) * 4;
#pragma unroll
    for (int mi = 0; mi < 4; mi++) {
      int m0 = bm + wm + mi * 16 + quad * 4;
      int bq2 = m0 >> 11, key = m0 & 2047;
      int kt = key >> 6;
      int k16 = (mi * 2 + (quad >> 1)) & 3;
      int half = mi >> 1;
#pragma unroll
      for (int ni = 0; ni < 4; ni++) {
        int e = bn + wn + ni * 16 + col;
        int h = e >> 6, d = e & 63;
        int nb = d >> 4, cl = d & 15;
        size_t seg = ((((size_t)(bq2 * 16 + h) * 32 + kt) * 4 + nb) * 2 + half);
        size_t off = seg * 512 + (size_t)(k16 * 16 + cl) * 8 + k7base;
        *(uint2*)(Vf + off) = make_uint2(pk2rne(av[mi][ni][0], av[mi][ni][1]),
                                         pk2rne(av[mi][ni][2], av[mi][ni][3]));
      }
    }
  }
}

__global__ __launch_bounds__(256) void out_gemm(const short* __restrict__ Ctx,
                                                const short* __restrict__ Wo,
                                                float* __restrict__ C) {
  __shared__ __align__(16) short sm[3 * 64 * 32 + 3 * 128 * 32];    // 36 KB
  gemm_core<float, 2, 4, false, EPI_ROW, false>(sm, sm + 3 * 64 * 32, Ctx, Wo, C,
                                                blockIdx.x * 64, blockIdx.y * 128, 1024, nullptr);
}

// ---------------------------------------------------------------------------
// Flash attention, causal. grid (bh=32, y=32), 256 threads = 4 waves, each
// wave = one 16-row strip of the block's 64-row qtile. K/V LDS-staged,
// double-buffered, vmcnt(0)+s_barrier per ktile. Software-pipelined:
// iter kt: QK(kt) + PV(kt-1) [reg-held P/V frags], then softmax(kt).
// Diag ktile peeled. setprio(1) around MFMA clusters. LPT qt permutation.
// ---------------------------------------------------------------------------
__global__ __launch_bounds__(256, 3) void flash_attn(const short* __restrict__ Q,
                                                     const short* __restrict__ Kf,
                                                     const short* __restrict__ Vf,
                                                     short* __restrict__ ctx) {
  const int y = blockIdx.y;
  const int g = y >> 3, r8 = y & 7;
  const int qt = (g == 0) ? 31 - r8 : (g == 1) ? r8 : (g == 2) ? 23 - r8 : 8 + r8;
  const int bh = blockIdx.x;
  const int b = bh >> 4, h = bh & 15;
  __shared__ __align__(16) short Ps[4][16 * 72];
  __shared__ __align__(16) short Ksm[2][4096];
  __shared__ __align__(16) short Vsm[2][4096];
  const int tid = threadIdx.x, lane = tid & 63, wave = tid >> 6;
  const int col = lane & 15, quad = lane >> 4;

  const short* Kg = Kf + (size_t)bh * 131072;
  const short* Vg = Vf + (size_t)bh * 131072;

  const float C1 = 0.18033688011112042f;    // 0.125 * log2(e)
  const float mC2 = -17.31234049066756f;    // -12 * log2(e)

  short* myPs = &Ps[wave][0];
  const int cx = col & 3;
  const int pswr0 = col * 72 + ((0 ^ cx) << 4) + quad * 4;
  const int pswr1 = col * 72 + ((1 ^ cx) << 4) + quad * 4;
  const int pswr2 = col * 72 + ((2 ^ cx) << 4) + quad * 4;
  const int pswr3 = col * 72 + ((3 ^ cx) << 4) + quad * 4;
  const int psrd0 = col * 72 + (((quad >> 1) ^ cx) << 4) + (quad & 1) * 8;
  const int psrd1 = col * 72 + ((((quad >> 1) + 2) ^ cx) << 4) + (quad & 1) * 8;

  auto stageKV = [&](int kt, short* kb, short* vb) {
    const short* kg = Kg + kt * 4096;
    const short* vg = Vg + kt * 4096;
#pragma unroll
    for (int c = tid; c < 512; c += 256) {
      async16(kg + c * 8, kb + c * 8);
      async16(vg + c * 8, vb + c * 8);
    }
  };

  const size_t qrow = (size_t)(b * 2048 + qt * 64 + wave * 16 + col);
  bf16x8 qf0 = *(const bf16x8*)(Q + qrow * 1024 + h * 64 + quad * 8);
  bf16x8 qf1 = *(const bf16x8*)(Q + qrow * 1024 + h * 64 + 32 + quad * 8);

  float l_i = 0.f;
  f32x4 o_acc[4];
#pragma unroll
  for (int i = 0; i < 4; i++) o_acc[i] = (f32x4){0.f, 0.f, 0.f, 0.f};

  short *kcur = &Ksm[0][0], *vcur = &Vsm[0][0];
  short *knxt = &Ksm[1][0], *vnxt = &Vsm[1][0];

  stageKV(0, kcur, vcur);
  asm volatile("s_waitcnt vmcnt(0)" ::: "memory");
  __builtin_amdgcn_s_barrier();

  bf16x8 afp0 = (bf16x8){0,0,0,0,0,0,0,0}, afp1 = (bf16x8){0,0,0,0,0,0,0,0};
  bf16x8 vfp[4][2];
#pragma unroll
  for (int i = 0; i < 4; i++) vfp[i][0] = vfp[i][1] = (bf16x8){0,0,0,0,0,0,0,0};

  for (int kt = 0; kt < qt; ++kt) {
    stageKV(kt + 1, knxt, vnxt);

    bf16x8 kfr[4][2];
#pragma unroll
    for (int nb = 0; nb < 4; nb++) {
      kfr[nb][0] = *(const bf16x8*)(kcur + (nb * 2 + 0) * 512 + lane * 8);
      kfr[nb][1] = *(const bf16x8*)(kcur + (nb * 2 + 1) * 512 + lane * 8);
    }

    f32x4 s_acc[4];
    __builtin_amdgcn_s_setprio(1);
#pragma unroll
    for (int nb = 0; nb < 4; nb++) {
      f32x4 z = (f32x4){0.f, 0.f, 0.f, 0.f};
      z = __builtin_amdgcn_mfma_f32_16x16x32_bf16(kfr[nb][0], qf0, z, 0, 0, 0);
      z = __builtin_amdgcn_mfma_f32_16x16x32_bf16(kfr[nb][1], qf1, z, 0, 0, 0);
      s_acc[nb] = z;
    }
    if (kt > 0) {
#pragma unroll
      for (int nb = 0; nb < 4; nb++) {
        o_acc[nb] = __builtin_amdgcn_mfma_f32_16x16x32_bf16(afp0, vfp[nb][0], o_acc[nb], 0, 0, 0);
        o_acc[nb] = __builtin_amdgcn_mfma_f32_16x16x32_bf16(afp1, vfp[nb][1], o_acc[nb], 0, 0, 0);
      }
    }
    __builtin_amdgcn_s_setprio(0);

#pragma unroll
    for (int nb = 0; nb < 4; nb++) {
      vfp[nb][0] = *(const bf16x8*)(vcur + (nb * 2 + 0) * 512 + lane * 8);
      vfp[nb][1] = *(const bf16x8*)(vcur + (nb * 2 + 1) * 512 + lane * 8);
    }

#pragma unroll
    for (int nb = 0; nb < 4; nb++) {
      float p0 = exp2x(fmaf(s_acc[nb][0], C1, mC2));
      float p1 = exp2x(fmaf(s_acc[nb][1], C1, mC2));
      float p2 = exp2x(fmaf(s_acc[nb][2], C1, mC2));
      float p3 = exp2x(fmaf(s_acc[nb][3], C1, mC2));
      int wr = (nb == 0) ? pswr0 : (nb == 1) ? pswr1 : (nb == 2) ? pswr2 : pswr3;
      *(uint2*)(myPs + wr) = make_uint2(pk2(p0, p1), pk2(p2, p3));
      l_i += (p0 + p1) + (p2 + p3);
    }
    afp0 = *(const bf16x8*)(myPs + psrd0);
    afp1 = *(const bf16x8*)(myPs + psrd1);

    asm volatile("s_waitcnt vmcnt(0)" ::: "memory");
    __builtin_amdgcn_s_barrier();
    short* t;
    t = kcur; kcur = knxt; knxt = t;
    t = vcur; vcur = vnxt; vnxt = t;
  }

  {
    const int ql = wave * 16 + col;
    const int kl = quad * 4;

    bf16x8 kfr[4][2];
#pragma unroll
    for (int nb = 0; nb < 4; nb++) {
      kfr[nb][0] = *(const bf16x8*)(kcur + (nb * 2 + 0) * 512 + lane * 8);
      kfr[nb][1] = *(const bf16x8*)(kcur + (nb * 2 + 1) * 512 + lane * 8);
    }

    f32x4 s_acc[4];
    __builtin_amdgcn_s_setprio(1);
#pragma unroll
    for (int nb = 0; nb < 4; nb++) {
      f32x4 z = (f32x4){0.f, 0.f, 0.f, 0.f};
      z = __builtin_amdgcn_mfma_f32_16x16x32_bf16(kfr[nb][0], qf0, z, 0, 0, 0);
      z = __builtin_amdgcn_mfma_f32_16x16x32_bf16(kfr[nb][1], qf1, z, 0, 0, 0);
      s_acc[nb] = z;
    }
    if (qt > 0) {
#pragma unroll
      for (int nb = 0; nb < 4; nb++) {
        o_acc[nb] = __builtin_amdgcn_mfma_f32_16x16x32_bf16(afp0, vfp[nb][0], o_acc[nb], 0, 0, 0);
        o_acc[nb] = __builtin_amdgcn_mfma_f32_16x16x32_bf16(afp1, vfp[nb][1], o_acc[nb], 0, 0, 0);
      }
    }
    __builtin_amdgcn_s_setprio(0);

#pragma unroll
    for (int nb = 0; nb < 4; nb++) {
      vfp[nb][0] = *(const bf16x8*)(vcur + (nb * 2 + 0) * 512 + lane * 8);
      vfp[nb][1] = *(const bf16x8*)(vcur + (nb * 2 + 1) * 512 + lane * 8);
    }

#pragma unroll
    for (int nb = 0; nb < 4; nb++) {
      float pv[4];
#pragma unroll
      for (int r = 0; r < 4; r++) {
        pv[r] = exp2x(fmaf(s_acc[nb][r], C1, mC2));
        if ((nb * 16 + kl + r) > ql) pv[r] = 0.f;
      }
      int wr = (nb == 0) ? pswr0 : (nb == 1) ? pswr1 : (nb == 2) ? pswr2 : pswr3;
      *(uint2*)(myPs + wr) = make_uint2(pk2(pv[0], pv[1]), pk2(pv[2], pv[3]));
      l_i += (pv[0] + pv[1]) + (pv[2] + pv[3]);
    }
    afp0 = *(const bf16x8*)(myPs + psrd0);
    afp1 = *(const bf16x8*)(myPs + psrd1);

    __builtin_amdgcn_s_setprio(1);
#pragma unroll
    for (int nb = 0; nb < 4; nb++) {
      o_acc[nb] = __builtin_amdgcn_mfma_f32_16x16x32_bf16(afp0, vfp[nb][0], o_acc[nb], 0, 0, 0);
      o_acc[nb] = __builtin_amdgcn_mfma_f32_16x16x32_bf16(afp1, vfp[nb][1], o_acc[nb], 0, 0, 0);
    }
    __builtin_amdgcn_s_setprio(0);
  }

  l_i += __shfl_xor(l_i, 16);
  l_i += __shfl_xor(l_i, 32);
  float invl = 1.0f / l_i;

#pragma unroll
  for (int r = 0; r < 4; r++) {
    float inv = __shfl(invl, quad * 4 + r);
    size_t row = (size_t)(b * 2048 + qt * 64 + wave * 16 + quad * 4 + r);
#pragma unroll
    for (int nb = 0; nb < 4; nb++)
      ctx[row * 1024 + h * 64 + nb * 16 + col] = f2bf(o_acc[nb][r] * inv);
  }
}

// ---------------------------------------------------------------------------
extern "C" void kernel_launch(void* const* d_in, const int* in_sizes, int n_in,
                              void* d_out, int out_size, void* d_ws, size_t ws_size,
                              hipStream_t stream) {
  const float* X  = (const float*)d_in[0];
  const int* pos  = (const int*)d_in[1];
  const float* wq = (const float*)d_in[2];
  const float* wk = (const float*)d_in[3];
  const float* wv = (const float*)d_in[4];
  const float* wo = (const float*)d_in[5];
  float* out = (float*)d_out;

  short* Xb  = (short*)d_ws;
  short* Wqb = Xb + (1 << 22);
  short* Wkb = Wqb + (1 << 20);
  short* Wvb = Wkb + (1 << 20);
  short* Wob = Wvb + (1 << 20);
  short* Qb  = Wob + (1 << 20);
  short* Kfb = Qb + (1 << 22);
  short* Vfb = Kfb + (1 << 22);
  short* Ctx = Vfb + (1 << 22);

  cast_all<<<8192, 256, 0, stream>>>((const float4*)X, (const float4*)wq, (const float4*)wk,
                                     (const float4*)wv, (const float4*)wo, Xb, Wqb);
  qkv_gemm<<<dim3(32, 8), 256, 0, stream>>>(Xb, Wqb, Wkb, Wvb, Qb, Kfb, Vfb, pos);
  flash_attn<<<dim3(32, 32), 256, 0, stream>>>(Qb, Kfb, Vfb, Ctx);
  out_gemm<<<dim3(64, 8), 256, 0, stream>>>(Ctx, Wob, out);
}

// Round 10
// 163.907 us; speedup vs baseline: 1.3628x; 1.3628x over previous
//
#include <hip/hip_runtime.h>

// ---------------------------------------------------------------------------
// Multihead self-attention with RoPE, MI355X (gfx950).  Round 19 (= R16 restore).
// B=2, S=2048, H=16, DH=64, DM=1024.
// R18 failure diagnosed: launch_bounds(256,2) caps unified VGPR+AGPR at 256;
// triple-merge needs ~300 (192 accum regs) -> allocator spilled accumulators
// to scratch (VGPR 212->128, WRITE_SIZE +12 MB, 96 us). Dual-merge QK is the
// register-feasible merge level (128 accum + ~84 overhead = 212 <= 256 at
// 2 blocks/CU). This file restores R16 verbatim (best measured: 166.9 total,
// qkv <= 42.8): dual-B QK GEMM sharing A=X (3-ring, vmcnt(6) counted),
// V GEMM separate (z=1), out_gemm 64x128 grid (64,8), pipelined flash with
// LPT qt permutation, d-permuted in-lane RoPE.
// ---------------------------------------------------------------------------

typedef __attribute__((ext_vector_type(8))) short bf16x8;
typedef __attribute__((ext_vector_type(4))) float f32x4;

__device__ __forceinline__ short f2bf(float f) {
  unsigned u = __float_as_uint(f);
  unsigned r = (u + 0x7fffu + ((u >> 16) & 1u)) >> 16;   // RNE
  return (short)(r & 0xFFFFu);
}

// pack two f32 -> adjacent bf16 (round-half-up via +0x8000), one v_perm_b32
__device__ __forceinline__ unsigned pk2(float a, float b) {
  return __builtin_amdgcn_perm(__float_as_uint(b) + 0x8000u,
                               __float_as_uint(a) + 0x8000u, 0x07060302u);
}

// native 2^x, one v_exp_f32 (bypasses OCML guard sequence)
__device__ __forceinline__ float exp2x(float x) {
  float r;
  asm("v_exp_f32 %0, %1" : "=v"(r) : "v"(x));
  return r;
}

// async global->LDS, 16B per lane. LDS dest must be wave-uniform base + lane*16.
__device__ __forceinline__ void async16(const void* g, void* l) {
  __builtin_amdgcn_global_load_lds(
      (const __attribute__((address_space(1))) void*)g,
      (__attribute__((address_space(3))) void*)l, 16, 0, 0);
}

__device__ __forceinline__ void cstore(short* C, size_t i, float v) { C[i] = f2bf(v); }
__device__ __forceinline__ void cstore(float* C, size_t i, float v) { C[i] = v; }

// ---------------------------------------------------------------------------
// merged f32 -> bf16 cast: X (1M float4) then Wq|Wk|Wv|Wo (dsts contiguous).
// ---------------------------------------------------------------------------
__global__ void cast_all(const float4* __restrict__ X,
                         const float4* __restrict__ w0, const float4* __restrict__ w1,
                         const float4* __restrict__ w2, const float4* __restrict__ w3,
                         short* __restrict__ Xb, short* __restrict__ Wb) {
  int t = blockIdx.x * 256 + threadIdx.x;
  const float4* s;
  short4* d;
  if (t < (1 << 20)) {
    s = X + t; d = (short4*)Xb + t;
  } else {
    int u = t - (1 << 20);
    int which = u >> 18;
    s = ((which == 0) ? w0 : (which == 1) ? w1 : (which == 2) ? w2 : w3) + (u & 0x3FFFF);
    d = (short4*)Wb + u;
  }
  float4 v = *s;
  *d = make_short4(f2bf(v.x), f2bf(v.y), f2bf(v.z), f2bf(v.w));
}

// ---------------------------------------------------------------------------
// bf16 GEMM core (single-B): C[M,N] = A[M,K] * B[N,K]^T, K=1024.
// 3-ring counted vmcnt. Used for V (EPI_VFRAG) and out_gemm (EPI_ROW).
// ---------------------------------------------------------------------------
enum EpiMode { EPI_ROW, EPI_KFRAG, EPI_VFRAG };

template <typename OUT, int MR, int NR, bool ROPE, EpiMode EM, bool MAPB>
__device__ __forceinline__ void gemm_core(short* __restrict__ As, short* __restrict__ Bs,
                                          const short* __restrict__ A, const short* __restrict__ B,
                                          OUT* __restrict__ C, int bm, int bn, int ldc,
                                          const int* __restrict__ pos) {
  constexpr int BM = 32 * MR, BN = 32 * NR;
  constexpr int NLD = (BM * 4 + BN * 4) / 256;   // global_load_lds per wave per stage
  const int tid  = threadIdx.x;
  const int lane = tid & 63, wave = tid >> 6;
  const int col  = lane & 15, quad = lane >> 4;
  const int wm = (wave & 1) * (16 * MR), wn = (wave >> 1) * (16 * NR);

  f32x4 acc[MR][NR];
#pragma unroll
  for (int i = 0; i < MR; i++)
#pragma unroll
    for (int j = 0; j < NR; j++) acc[i][j] = (f32x4){0.f, 0.f, 0.f, 0.f};

  auto stage = [&](int k0, int bu) {
#pragma unroll
    for (int c = tid; c < BM * 4; c += 256) {
      int r = c >> 2, cc = (c & 3) << 3;
      async16(A + (size_t)(bm + r) * 1024 + k0 + cc, As + bu * BM * 32 + c * 8);
    }
#pragma unroll
    for (int c = tid; c < BN * 4; c += 256) {
      int r = c >> 2, cc = (c & 3) << 3;
      int rg = bn + r;
      if (MAPB) {
        int k6 = rg & 63;
        rg = (rg & ~63) | ((k6 < 32) ? (k6 << 1) : (((k6 - 32) << 1) | 1));
      }
      async16(B + (size_t)rg * 1024 + k0 + cc, Bs + bu * BN * 32 + c * 8);
    }
  };

  // prologue: 2 stages in flight, wait for stage 0 only (vmcnt leaves NLD).
  stage(0, 0);
  stage(32, 1);
  if constexpr (NLD == 4) asm volatile("s_waitcnt vmcnt(4)" ::: "memory");
  else                    asm volatile("s_waitcnt vmcnt(3)" ::: "memory");
  __builtin_amdgcn_s_barrier();

  int cur = 0, nxt = 2;
  for (int it = 0; it < 32; ++it) {
    if (it < 30) stage((it + 2) * 32, nxt);
    const short* as = As + cur * (BM * 32);
    const short* bs = Bs + cur * (BN * 32);

    bf16x8 af[MR], bfr[NR];
#pragma unroll
    for (int i = 0; i < MR; i++)
      af[i] = *(const bf16x8*)(as + (wm + i * 16 + col) * 32 + quad * 8);
#pragma unroll
    for (int i = 0; i < NR; i++)
      bfr[i] = *(const bf16x8*)(bs + (wn + i * 16 + col) * 32 + quad * 8);
#pragma unroll
    for (int mi = 0; mi < MR; mi++)
#pragma unroll
      for (int ni = 0; ni < NR; ni++)
        acc[mi][ni] = __builtin_amdgcn_mfma_f32_16x16x32_bf16(af[mi], bfr[ni], acc[mi][ni], 0, 0, 0);

    // counted drain: oldest stage (it+1) must have landed; newest (it+2) may fly.
    if (it < 30) {
      if constexpr (NLD == 4) asm volatile("s_waitcnt vmcnt(4)" ::: "memory");
      else                    asm volatile("s_waitcnt vmcnt(3)" ::: "memory");
    } else {
      asm volatile("s_waitcnt vmcnt(0)" ::: "memory");
    }
    __builtin_amdgcn_s_barrier();
    cur = (cur == 2) ? 0 : cur + 1;
    nxt = (nxt == 2) ? 0 : nxt + 1;
  }

  if (ROPE) {
    float invf[2];
#pragma unroll
    for (int ni = 0; ni < 2; ni++) {
      int p = ni * 16 + col;
      invf[ni] = exp2f(-0.4152410118609203f * (float)p) * 0.15915494309189535f;
    }
#pragma unroll
    for (int mi = 0; mi < MR; mi++) {
#pragma unroll
      for (int r = 0; r < 4; r++) {
        int row = bm + wm + mi * 16 + quad * 4 + r;
        float fp = (float)pos[row & 2047];
#pragma unroll
        for (int ni = 0; ni < 2; ni++) {
          float rev = fp * invf[ni];
          rev -= floorf(rev);
          float sn = __builtin_amdgcn_sinf(rev);
          float cs = __builtin_amdgcn_cosf(rev);
          float x  = acc[mi][ni][r];
          float yv = acc[mi][ni + 2][r];
          acc[mi][ni][r]     = fmaf(x, cs, -yv * sn);
          acc[mi][ni + 2][r] = fmaf(yv, cs, x * sn);
        }
      }
    }
  }

  if (EM == EPI_ROW) {
#pragma unroll
    for (int mi = 0; mi < MR; mi++) {
#pragma unroll
      for (int r = 0; r < 4; r++) {
        size_t row = (size_t)(bm + wm + mi * 16 + quad * 4 + r);
#pragma unroll
        for (int ni = 0; ni < NR; ni++) {
          int cg = bn + wn + ni * 16 + col;
          cstore(C, row * ldc + cg, acc[mi][ni][r]);
        }
      }
    }
  } else if (EM == EPI_KFRAG) {
#pragma unroll
    for (int mi = 0; mi < MR; mi++) {
#pragma unroll
      for (int r = 0; r < 4; r++) {
        int m = bm + wm + mi * 16 + quad * 4 + r;
        int bq = m >> 11, key = m & 2047;
        int kt = key >> 6, nb = (key >> 4) & 3, cl = key & 15;
#pragma unroll
        for (int ni = 0; ni < NR; ni++) {
          int e = bn + wn + ni * 16 + col;
          int h = e >> 6, d = e & 63;
          size_t seg = ((((size_t)(bq * 16 + h) * 32 + kt) * 4 + nb) * 2 + (d >> 5));
          cstore((short*)C, seg * 512 + (((d >> 3) & 3) * 16 + cl) * 8 + (d & 7), acc[mi][ni][r]);
        }
      }
    }
  } else {   // EPI_VFRAG
#pragma unroll
    for (int mi = 0; mi < MR; mi++) {
#pragma unroll
      for (int r = 0; r < 4; r++) {
        int e = bm + wm + mi * 16 + quad * 4 + r;
        int h = e >> 6, d = e & 63;
        int nb = d >> 4, cl = d & 15;
#pragma unroll
        for (int ni = 0; ni < NR; ni++) {
          int m = bn + wn + ni * 16 + col;
          int bq = m >> 11, key = m & 2047;
          int kt = key >> 6, k64 = key & 63;
          size_t seg = ((((size_t)(bq * 16 + h) * 32 + kt) * 4 + nb) * 2 + (k64 >> 5));
          cstore((short*)C, seg * 512 + (((k64 >> 3) & 3) * 16 + cl) * 8 + (k64 & 7), acc[mi][ni][r]);
        }
      }
    }
  }
}

// ---------------------------------------------------------------------------
// Merged dual-B GEMM: Q = rope(X Wq^T) row-major AND Kf = rope(X Wk^T)
// frag-major, sharing the A=X tile. BM=BN=128, BK=32, 3-ring.
// Per stage per thread: 2 A + 2 Bq + 2 Bk = 6 async16 -> vmcnt(6).
// Register-feasible merge: 128 accum + ~84 overhead = 212 <= 256 budget.
// ---------------------------------------------------------------------------
__device__ __forceinline__ void gemm_qk(short* __restrict__ As, short* __restrict__ Bqs,
                                        short* __restrict__ Bks,
                                        const short* __restrict__ A,
                                        const short* __restrict__ Bq,
                                        const short* __restrict__ Bk,
                                        short* __restrict__ Qo, short* __restrict__ Kf,
                                        int bm, int bn, const int* __restrict__ pos) {
  const int tid  = threadIdx.x;
  const int lane = tid & 63, wave = tid >> 6;
  const int col  = lane & 15, quad = lane >> 4;
  const int wm = (wave & 1) * 64, wn = (wave >> 1) * 64;

  f32x4 aq[4][4], ak[4][4];
#pragma unroll
  for (int i = 0; i < 4; i++)
#pragma unroll
    for (int j = 0; j < 4; j++) {
      aq[i][j] = (f32x4){0.f, 0.f, 0.f, 0.f};
      ak[i][j] = (f32x4){0.f, 0.f, 0.f, 0.f};
    }

  auto stage = [&](int k0, int bu) {
#pragma unroll
    for (int c = tid; c < 512; c += 256) {
      int r = c >> 2, cc = (c & 3) << 3;
      async16(A + (size_t)(bm + r) * 1024 + k0 + cc, As + bu * 4096 + c * 8);
    }
#pragma unroll
    for (int c = tid; c < 512; c += 256) {
      int r = c >> 2, cc = (c & 3) << 3;
      int rg = bn + r;
      int k6 = rg & 63;
      rg = (rg & ~63) | ((k6 < 32) ? (k6 << 1) : (((k6 - 32) << 1) | 1));
      async16(Bq + (size_t)rg * 1024 + k0 + cc, Bqs + bu * 4096 + c * 8);
      async16(Bk + (size_t)rg * 1024 + k0 + cc, Bks + bu * 4096 + c * 8);
    }
  };

  stage(0, 0);
  stage(32, 1);
  asm volatile("s_waitcnt vmcnt(6)" ::: "memory");
  __builtin_amdgcn_s_barrier();

  int cur = 0, nxt = 2;
  for (int it = 0; it < 32; ++it) {
    if (it < 30) stage((it + 2) * 32, nxt);
    const short* as = As + cur * 4096;
    const short* bq = Bqs + cur * 4096;
    const short* bk = Bks + cur * 4096;

    bf16x8 af[4], bfq[4], bfk[4];
#pragma unroll
    for (int i = 0; i < 4; i++)
      af[i] = *(const bf16x8*)(as + (wm + i * 16 + col) * 32 + quad * 8);
#pragma unroll
    for (int i = 0; i < 4; i++) {
      bfq[i] = *(const bf16x8*)(bq + (wn + i * 16 + col) * 32 + quad * 8);
      bfk[i] = *(const bf16x8*)(bk + (wn + i * 16 + col) * 32 + quad * 8);
    }
#pragma unroll
    for (int mi = 0; mi < 4; mi++)
#pragma unroll
      for (int ni = 0; ni < 4; ni++) {
        aq[mi][ni] = __builtin_amdgcn_mfma_f32_16x16x32_bf16(af[mi], bfq[ni], aq[mi][ni], 0, 0, 0);
        ak[mi][ni] = __builtin_amdgcn_mfma_f32_16x16x32_bf16(af[mi], bfk[ni], ak[mi][ni], 0, 0, 0);
      }

    if (it < 30) asm volatile("s_waitcnt vmcnt(6)" ::: "memory");
    else         asm volatile("s_waitcnt vmcnt(0)" ::: "memory");
    __builtin_amdgcn_s_barrier();
    cur = (cur == 2) ? 0 : cur + 1;
    nxt = (nxt == 2) ? 0 : nxt + 1;
  }

  // shared RoPE: sn/cs identical for Q and K (same row/col) — computed once.
  float invf[2];
#pragma unroll
  for (int ni = 0; ni < 2; ni++) {
    int p = ni * 16 + col;
    invf[ni] = exp2f(-0.4152410118609203f * (float)p) * 0.15915494309189535f;
  }
#pragma unroll
  for (int mi = 0; mi < 4; mi++) {
#pragma unroll
    for (int r = 0; r < 4; r++) {
      int row = bm + wm + mi * 16 + quad * 4 + r;
      float fp = (float)pos[row & 2047];
#pragma unroll
      for (int ni = 0; ni < 2; ni++) {
        float rev = fp * invf[ni];
        rev -= floorf(rev);
        float sn = __builtin_amdgcn_sinf(rev);
        float cs = __builtin_amdgcn_cosf(rev);
        float xq = aq[mi][ni][r], yq = aq[mi][ni + 2][r];
        aq[mi][ni][r]     = fmaf(xq, cs, -yq * sn);
        aq[mi][ni + 2][r] = fmaf(yq, cs, xq * sn);
        float xk = ak[mi][ni][r], yk = ak[mi][ni + 2][r];
        ak[mi][ni][r]     = fmaf(xk, cs, -yk * sn);
        ak[mi][ni + 2][r] = fmaf(yk, cs, xk * sn);
      }
    }
  }

  // Q epilogue: row-major
#pragma unroll
  for (int mi = 0; mi < 4; mi++) {
#pragma unroll
    for (int r = 0; r < 4; r++) {
      size_t row = (size_t)(bm + wm + mi * 16 + quad * 4 + r);
#pragma unroll
      for (int ni = 0; ni < 4; ni++) {
        int cg = bn + wn + ni * 16 + col;
        Qo[row * 1024 + cg] = f2bf(aq[mi][ni][r]);
      }
    }
  }
  // K epilogue: fragment-major
#pragma unroll
  for (int mi = 0; mi < 4; mi++) {
#pragma unroll
    for (int r = 0; r < 4; r++) {
      int m = bm + wm + mi * 16 + quad * 4 + r;
      int bq2 = m >> 11, key = m & 2047;
      int kt = key >> 6, nb = (key >> 4) & 3, cl = key & 15;
#pragma unroll
      for (int ni = 0; ni < 4; ni++) {
        int e = bn + wn + ni * 16 + col;
        int h = e >> 6, d = e & 63;
        size_t seg = ((((size_t)(bq2 * 16 + h) * 32 + kt) * 4 + nb) * 2 + (d >> 5));
        Kf[seg * 512 + (((d >> 3) & 3) * 16 + cl) * 8 + (d & 7)] = f2bf(ak[mi][ni][r]);
      }
    }
  }
}

// z=0: merged QK (d-permuted RoPE); z=1: Vf = Wv X^T frag-major.
__global__ __launch_bounds__(256, 2) void qkv_gemm(const short* __restrict__ Xb,
                                                   const short* __restrict__ Wq,
                                                   const short* __restrict__ Wk,
                                                   const short* __restrict__ Wv,
                                                   short* __restrict__ Qo,
                                                   short* __restrict__ Kf,
                                                   short* __restrict__ Vf,
                                                   const int* __restrict__ pos) {
  __shared__ __align__(16) short sm[3 * 4096 * 3];   // 72 KB (3 operands x 3-ring)
  if (blockIdx.z == 0)
    gemm_qk(sm, sm + 12288, sm + 24576, Xb, Wq, Wk, Qo, Kf,
            blockIdx.x * 128, blockIdx.y * 128, pos);
  else
    gemm_core<short, 4, 4, false, EPI_VFRAG, false>(sm, sm + 12288, Wv, Xb, Vf,
                                                    blockIdx.y * 128, blockIdx.x * 128, 0, pos);
}

__global__ __launch_bounds__(256) void out_gemm(const short* __restrict__ Ctx,
                                                const short* __restrict__ Wo,
                                                float* __restrict__ C) {
  __shared__ __align__(16) short sm[3 * 64 * 32 + 3 * 128 * 32];    // 36 KB
  gemm_core<float, 2, 4, false, EPI_ROW, false>(sm, sm + 3 * 64 * 32, Ctx, Wo, C,
                                                blockIdx.x * 64, blockIdx.y * 128, 1024, nullptr);
}

// ---------------------------------------------------------------------------
// Flash attention, causal. grid (bh=32, y=32), 256 threads = 4 waves, each
// wave = one 16-row strip of the block's 64-row qtile. K/V LDS-staged,
// double-buffered, vmcnt(0)+s_barrier per ktile. Software-pipelined:
// iter kt: QK(kt) + PV(kt-1) [reg-held P/V frags], then softmax(kt).
// Diag ktile peeled. setprio(1) around MFMA clusters. LPT qt permutation.
// ---------------------------------------------------------------------------
__global__ __launch_bounds__(256, 3) void flash_attn(const short* __restrict__ Q,
                                                     const short* __restrict__ Kf,
                                                     const short* __restrict__ Vf,
                                                     short* __restrict__ ctx) {
  const int y = blockIdx.y;
  const int g = y >> 3, r8 = y & 7;
  const int qt = (g == 0) ? 31 - r8 : (g == 1) ? r8 : (g == 2) ? 23 - r8 : 8 + r8;
  const int bh = blockIdx.x;
  const int b = bh >> 4, h = bh & 15;
  __shared__ __align__(16) short Ps[4][16 * 72];
  __shared__ __align__(16) short Ksm[2][4096];
  __shared__ __align__(16) short Vsm[2][4096];
  const int tid = threadIdx.x, lane = tid & 63, wave = tid >> 6;
  const int col = lane & 15, quad = lane >> 4;

  const short* Kg = Kf + (size_t)bh * 131072;
  const short* Vg = Vf + (size_t)bh * 131072;

  const float C1 = 0.18033688011112042f;    // 0.125 * log2(e)
  const float mC2 = -17.31234049066756f;    // -12 * log2(e)

  short* myPs = &Ps[wave][0];
  const int cx = col & 3;
  const int pswr0 = col * 72 + ((0 ^ cx) << 4) + quad * 4;
  const int pswr1 = col * 72 + ((1 ^ cx) << 4) + quad * 4;
  const int pswr2 = col * 72 + ((2 ^ cx) << 4) + quad * 4;
  const int pswr3 = col * 72 + ((3 ^ cx) << 4) + quad * 4;
  const int psrd0 = col * 72 + (((quad >> 1) ^ cx) << 4) + (quad & 1) * 8;
  const int psrd1 = col * 72 + ((((quad >> 1) + 2) ^ cx) << 4) + (quad & 1) * 8;

  auto stageKV = [&](int kt, short* kb, short* vb) {
    const short* kg = Kg + kt * 4096;
    const short* vg = Vg + kt * 4096;
#pragma unroll
    for (int c = tid; c < 512; c += 256) {
      async16(kg + c * 8, kb + c * 8);
      async16(vg + c * 8, vb + c * 8);
    }
  };

  const size_t qrow = (size_t)(b * 2048 + qt * 64 + wave * 16 + col);
  bf16x8 qf0 = *(const bf16x8*)(Q + qrow * 1024 + h * 64 + quad * 8);
  bf16x8 qf1 = *(const bf16x8*)(Q + qrow * 1024 + h * 64 + 32 + quad * 8);

  float l_i = 0.f;
  f32x4 o_acc[4];
#pragma unroll
  for (int i = 0; i < 4; i++) o_acc[i] = (f32x4){0.f, 0.f, 0.f, 0.f};

  short *kcur = &Ksm[0][0], *vcur = &Vsm[0][0];
  short *knxt = &Ksm[1][0], *vnxt = &Vsm[1][0];

  stageKV(0, kcur, vcur);
  asm volatile("s_waitcnt vmcnt(0)" ::: "memory");
  __builtin_amdgcn_s_barrier();

  bf16x8 afp0 = (bf16x8){0,0,0,0,0,0,0,0}, afp1 = (bf16x8){0,0,0,0,0,0,0,0};
  bf16x8 vfp[4][2];
#pragma unroll
  for (int i = 0; i < 4; i++) vfp[i][0] = vfp[i][1] = (bf16x8){0,0,0,0,0,0,0,0};

  for (int kt = 0; kt < qt; ++kt) {
    stageKV(kt + 1, knxt, vnxt);

    bf16x8 kfr[4][2];
#pragma unroll
    for (int nb = 0; nb < 4; nb++) {
      kfr[nb][0] = *(const bf16x8*)(kcur + (nb * 2 + 0) * 512 + lane * 8);
      kfr[nb][1] = *(const bf16x8*)(kcur + (nb * 2 + 1) * 512 + lane * 8);
    }

    f32x4 s_acc[4];
    __builtin_amdgcn_s_setprio(1);
#pragma unroll
    for (int nb = 0; nb < 4; nb++) {
      f32x4 z = (f32x4){0.f, 0.f, 0.f, 0.f};
      z = __builtin_amdgcn_mfma_f32_16x16x32_bf16(kfr[nb][0], qf0, z, 0, 0, 0);
      z = __builtin_amdgcn_mfma_f32_16x16x32_bf16(kfr[nb][1], qf1, z, 0, 0, 0);
      s_acc[nb] = z;
    }
    if (kt > 0) {
#pragma unroll
      for (int nb = 0; nb < 4; nb++) {
        o_acc[nb] = __builtin_amdgcn_mfma_f32_16x16x32_bf16(afp0, vfp[nb][0], o_acc[nb], 0, 0, 0);
        o_acc[nb] = __builtin_amdgcn_mfma_f32_16x16x32_bf16(afp1, vfp[nb][1], o_acc[nb], 0, 0, 0);
      }
    }
    __builtin_amdgcn_s_setprio(0);

#pragma unroll
    for (int nb = 0; nb < 4; nb++) {
      vfp[nb][0] = *(const bf16x8*)(vcur + (nb * 2 + 0) * 512 + lane * 8);
      vfp[nb][1] = *(const bf16x8*)(vcur + (nb * 2 + 1) * 512 + lane * 8);
    }

#pragma unroll
    for (int nb = 0; nb < 4; nb++) {
      float p0 = exp2x(fmaf(s_acc[nb][0], C1, mC2));
      float p1 = exp2x(fmaf(s_acc[nb][1], C1, mC2));
      float p2 = exp2x(fmaf(s_acc[nb][2], C1, mC2));
      float p3 = exp2x(fmaf(s_acc[nb][3], C1, mC2));
      int wr = (nb == 0) ? pswr0 : (nb == 1) ? pswr1 : (nb == 2) ? pswr2 : pswr3;
      *(uint2*)(myPs + wr) = make_uint2(pk2(p0, p1), pk2(p2, p3));
      l_i += (p0 + p1) + (p2 + p3);
    }
    afp0 = *(const bf16x8*)(myPs + psrd0);
    afp1 = *(const bf16x8*)(myPs + psrd1);

    asm volatile("s_waitcnt vmcnt(0)" ::: "memory");
    __builtin_amdgcn_s_barrier();
    short* t;
    t = kcur; kcur = knxt; knxt = t;
    t = vcur; vcur = vnxt; vnxt = t;
  }

  {
    const int ql = wave * 16 + col;
    const int kl = quad * 4;

    bf16x8 kfr[4][2];
#pragma unroll
    for (int nb = 0; nb < 4; nb++) {
      kfr[nb][0] = *(const bf16x8*)(kcur + (nb * 2 + 0) * 512 + lane * 8);
      kfr[nb][1] = *(const bf16x8*)(kcur + (nb * 2 + 1) * 512 + lane * 8);
    }

    f32x4 s_acc[4];
    __builtin_amdgcn_s_setprio(1);
#pragma unroll
    for (int nb = 0; nb < 4; nb++) {
      f32x4 z = (f32x4){0.f, 0.f, 0.f, 0.f};
      z = __builtin_amdgcn_mfma_f32_16x16x32_bf16(kfr[nb][0], qf0, z, 0, 0, 0);
      z = __builtin_amdgcn_mfma_f32_16x16x32_bf16(kfr[nb][1], qf1, z, 0, 0, 0);
      s_acc[nb] = z;
    }
    if (qt > 0) {
#pragma unroll
      for (int nb = 0; nb < 4; nb++) {
        o_acc[nb] = __builtin_amdgcn_mfma_f32_16x16x32_bf16(afp0, vfp[nb][0], o_acc[nb], 0, 0, 0);
        o_acc[nb] = __builtin_amdgcn_mfma_f32_16x16x32_bf16(afp1, vfp[nb][1], o_acc[nb], 0, 0, 0);
      }
    }
    __builtin_amdgcn_s_setprio(0);

#pragma unroll
    for (int nb = 0; nb < 4; nb++) {
      vfp[nb][0] = *(const bf16x8*)(vcur + (nb * 2 + 0) * 512 + lane * 8);
      vfp[nb][1] = *(const bf16x8*)(vcur + (nb * 2 + 1) * 512 + lane * 8);
    }

#pragma unroll
    for (int nb = 0; nb < 4; nb++) {
      float pv[4];
#pragma unroll
      for (int r = 0; r < 4; r++) {
        pv[r] = exp2x(fmaf(s_acc[nb][r], C1, mC2));
        if ((nb * 16 + kl + r) > ql) pv[r] = 0.f;
      }
      int wr = (nb == 0) ? pswr0 : (nb == 1) ? pswr1 : (nb == 2) ? pswr2 : pswr3;
      *(uint2*)(myPs + wr) = make_uint2(pk2(pv[0], pv[1]), pk2(pv[2], pv[3]));
      l_i += (pv[0] + pv[1]) + (pv[2] + pv[3]);
    }
    afp0 = *(const bf16x8*)(myPs + psrd0);
    afp1 = *(const bf16x8*)(myPs + psrd1);

    __builtin_amdgcn_s_setprio(1);
#pragma unroll
    for (int nb = 0; nb < 4; nb++) {
      o_acc[nb] = __builtin_amdgcn_mfma_f32_16x16x32_bf16(afp0, vfp[nb][0], o_acc[nb], 0, 0, 0);
      o_acc[nb] = __builtin_amdgcn_mfma_f32_16x16x32_bf16(afp1, vfp[nb][1], o_acc[nb], 0, 0, 0);
    }
    __builtin_amdgcn_s_setprio(0);
  }

  l_i += __shfl_xor(l_i, 16);
  l_i += __shfl_xor(l_i, 32);
  float invl = 1.0f / l_i;

#pragma unroll
  for (int r = 0; r < 4; r++) {
    float inv = __shfl(invl, quad * 4 + r);
    size_t row = (size_t)(b * 2048 + qt * 64 + wave * 16 + quad * 4 + r);
#pragma unroll
    for (int nb = 0; nb < 4; nb++)
      ctx[row * 1024 + h * 64 + nb * 16 + col] = f2bf(o_acc[nb][r] * inv);
  }
}

// ---------------------------------------------------------------------------
extern "C" void kernel_launch(void* const* d_in, const int* in_sizes, int n_in,
                              void* d_out, int out_size, void* d_ws, size_t ws_size,
                              hipStream_t stream) {
  const float* X  = (const float*)d_in[0];
  const int* pos  = (const int*)d_in[1];
  const float* wq = (const float*)d_in[2];
  const float* wk = (const float*)d_in[3];
  const float* wv = (const float*)d_in[4];
  const float* wo = (const float*)d_in[5];
  float* out = (float*)d_out;

  short* Xb  = (short*)d_ws;
  short* Wqb = Xb + (1 << 22);
  short* Wkb = Wqb + (1 << 20);
  short* Wvb = Wkb + (1 << 20);
  short* Wob = Wvb + (1 << 20);
  short* Qb  = Wob + (1 << 20);
  short* Kfb = Qb + (1 << 22);
  short* Vfb = Kfb + (1 << 22);
  short* Ctx = Vfb + (1 << 22);

  cast_all<<<8192, 256, 0, stream>>>((const float4*)X, (const float4*)wq, (const float4*)wk,
                                     (const float4*)wv, (const float4*)wo, Xb, Wqb);
  qkv_gemm<<<dim3(32, 8, 2), 256, 0, stream>>>(Xb, Wqb, Wkb, Wvb, Qb, Kfb, Vfb, pos);
  flash_attn<<<dim3(32, 32), 256, 0, stream>>>(Qb, Kfb, Vfb, Ctx);
  out_gemm<<<dim3(64, 8), 256, 0, stream>>>(Ctx, Wob, out);
}